// Round 1
// baseline (301.398 us; speedup 1.0000x reference)
//
#include <hip/hip_runtime.h>

// TFF_Angle: angle force-field energy + force scatter.
// Inputs (setup_inputs order):
//   0: dist_mat   (N,N)    float32
//   1: vector_mat (N,N,3)  float32
//   2: forces_out (N,3)    float32 (zeros; base for scatter)
//   3: params     (A,2)    float32 (k0, theta0)
//   4: coord_idx  (A,3)    int32
//   5: calc_energy scalar int32 (device)
//   6: calc_forces scalar int32 (device)
// Output: [energy (1 float)] ++ [forces (N*3 floats)]

__global__ void init_out_kernel(float* __restrict__ out,
                                const float* __restrict__ forces0,
                                int nf) {
    int j = blockIdx.x * blockDim.x + threadIdx.x;
    if (j == 0) out[0] = 0.0f;
    if (j < nf) out[1 + j] = forces0[j];
}

__global__ void __launch_bounds__(1024)
angle_kernel(const float* __restrict__ dist,
             const float* __restrict__ vec,
             const float* __restrict__ params,
             const int*   __restrict__ cidx,
             const int*   __restrict__ ce_p,
             const int*   __restrict__ cf_p,
             float* __restrict__ out,      // [0]=energy, [1..nf]=forces
             float* __restrict__ ws,       // n_part x nf partials (if use_ws)
             int use_ws,
             int n_atoms, int n_angles) {
    extern __shared__ float s_f[];        // nf = n_atoms*3 floats (48 KB at N=4096)
    __shared__ float s_e;
    const int nf  = n_atoms * 3;
    const int tid = threadIdx.x;

    for (int j = tid; j < nf; j += blockDim.x) s_f[j] = 0.0f;
    if (tid == 0) s_e = 0.0f;
    __syncthreads();

    const int ce = ce_p[0];
    const int cf = cf_p[0];

    float e_acc = 0.0f;
    const long stride = (long)gridDim.x * blockDim.x;
    for (long i = (long)blockIdx.x * blockDim.x + tid; i < n_angles; i += stride) {
        const int a1 = cidx[3 * i + 0];
        const int a2 = cidx[3 * i + 1];
        const int a3 = cidx[3 * i + 2];
        const float k0  = params[2 * i + 0];
        const float th0 = params[2 * i + 1];

        const long b21 = (long)a2 * n_atoms + a1;
        const long b23 = (long)a2 * n_atoms + a3;

        const float v21x = vec[b21 * 3 + 0];
        const float v21y = vec[b21 * 3 + 1];
        const float v21z = vec[b21 * 3 + 2];
        const float v23x = vec[b23 * 3 + 0];
        const float v23y = vec[b23 * 3 + 1];
        const float v23z = vec[b23 * 3 + 2];
        const float d21 = dist[b21];
        const float d23 = dist[b23];

        float c = v21x * v23x + v21y * v23y + v21z * v23z;
        c = fminf(1.0f, fmaxf(-1.0f, c));
        const float th  = acosf(c);
        const float dth = th - th0;

        if (ce) e_acc += k0 * dth * dth;

        if (cf) {
            const float s2 = fmaxf(0.0f, 1.0f - c * c);
            const float s  = sqrtf(s2);
            const float coef = (s > 0.0f) ? (-2.0f * k0 * dth / fmaxf(s, 1e-12f)) : 0.0f;
            const float i21 = coef / d21;
            const float i23 = coef / d23;

            const float f0x = i21 * (c * v21x - v23x);
            const float f0y = i21 * (c * v21y - v23y);
            const float f0z = i21 * (c * v21z - v23z);
            const float f2x = i23 * (c * v23x - v21x);
            const float f2y = i23 * (c * v23y - v21y);
            const float f2z = i23 * (c * v23z - v21z);
            const float f1x = -(f0x + f2x);
            const float f1y = -(f0y + f2y);
            const float f1z = -(f0z + f2z);

            atomicAdd(&s_f[a1 * 3 + 0], f0x);
            atomicAdd(&s_f[a1 * 3 + 1], f0y);
            atomicAdd(&s_f[a1 * 3 + 2], f0z);
            atomicAdd(&s_f[a2 * 3 + 0], f1x);
            atomicAdd(&s_f[a2 * 3 + 1], f1y);
            atomicAdd(&s_f[a2 * 3 + 2], f1z);
            atomicAdd(&s_f[a3 * 3 + 0], f2x);
            atomicAdd(&s_f[a3 * 3 + 1], f2y);
            atomicAdd(&s_f[a3 * 3 + 2], f2z);
        }
    }

    if (ce) {
        // wave-64 reduction, then per-block LDS reduce, one global atomic/block
        for (int off = 32; off > 0; off >>= 1)
            e_acc += __shfl_down(e_acc, off, 64);
        if ((tid & 63) == 0) atomicAdd(&s_e, e_acc);
    }
    __syncthreads();
    if (ce && tid == 0) atomicAdd(&out[0], s_e);

    if (use_ws) {
        float* w = ws + (long)blockIdx.x * nf;
        for (int j = tid; j < nf; j += blockDim.x) w[j] = s_f[j];
    } else if (cf) {
        for (int j = tid; j < nf; j += blockDim.x) {
            const float v = s_f[j];
            if (v != 0.0f) atomicAdd(&out[1 + j], v);
        }
    }
}

#define SEG 16

__global__ void reduce_kernel(const float* __restrict__ ws,
                              float* __restrict__ out,
                              int nf, int n_part) {
    const int comp = blockIdx.x * blockDim.x + threadIdx.x;
    if (comp >= nf) return;
    const int p0 = blockIdx.y * SEG;
    int p1 = p0 + SEG;
    if (p1 > n_part) p1 = n_part;
    float s = 0.0f;
    for (int p = p0; p < p1; ++p)
        s += ws[(long)p * nf + comp];
    if (s != 0.0f) atomicAdd(&out[1 + comp], s);
}

extern "C" void kernel_launch(void* const* d_in, const int* in_sizes, int n_in,
                              void* d_out, int out_size, void* d_ws, size_t ws_size,
                              hipStream_t stream) {
    const float* dist    = (const float*)d_in[0];
    const float* vec     = (const float*)d_in[1];
    const float* forces0 = (const float*)d_in[2];
    const float* params  = (const float*)d_in[3];
    const int*   cidx    = (const int*)d_in[4];
    const int*   ce_p    = (const int*)d_in[5];
    const int*   cf_p    = (const int*)d_in[6];
    float* out = (float*)d_out;

    const int n_atoms  = in_sizes[2] / 3;
    const int n_angles = in_sizes[4] / 3;
    const int nf = n_atoms * 3;

    // init output: energy=0, forces=forces_out base
    init_out_kernel<<<(nf + 1 + 255) / 256, 256, 0, stream>>>(out, forces0, nf);

    // workspace-partial path if scratch fits; else direct-atomic flush
    const size_t partial_bytes = (size_t)nf * sizeof(float);
    int n_part = 256;
    if (ws_size < (size_t)n_part * partial_bytes)
        n_part = (int)(ws_size / partial_bytes);
    const int use_ws = (n_part >= 8) ? 1 : 0;

    const int T = 1024;
    const int B = use_ws ? n_part : 256;
    const size_t lds_bytes = (size_t)nf * sizeof(float);  // 48 KB at N=4096

    angle_kernel<<<B, T, lds_bytes, stream>>>(dist, vec, params, cidx, ce_p, cf_p,
                                              out, (float*)d_ws, use_ws,
                                              n_atoms, n_angles);

    if (use_ws) {
        dim3 grid((nf + 255) / 256, (n_part + SEG - 1) / SEG);
        reduce_kernel<<<grid, 256, 0, stream>>>((const float*)d_ws, out, nf, n_part);
    }
}